// Round 8
// baseline (86.681 us; speedup 1.0000x reference)
//
#include <hip/hip_runtime.h>

#define HID 1024
#define BATCH 256
#define KTASK 4096
#define TPB 4                 // tasks per group
#define GROUPS 4              // groups per block
#define NROW 32               // TPB*8 LDS rows
#define HALF 512              // k-elems per unit (half K)
#define RSTR 1024             // LDS row stride bytes (512 bf16, swizzled, no pad)
#define BUFB (NROW * RSTR)    // 32 KB per buffer

typedef __bf16 bf16x8 __attribute__((ext_vector_type(8)));
typedef __bf16 bf16x4 __attribute__((ext_vector_type(4)));
typedef float f32x4 __attribute__((ext_vector_type(4)));

#define MFMA(a, b, c) __builtin_amdgcn_mfma_f32_16x16x32_bf16((a), (b), (c), 0, 0, 0)

__global__ __launch_bounds__(256, 4)
void cvt_emb_kernel(const float* __restrict__ emb, __bf16* __restrict__ dst) {
    int i = (blockIdx.x * 256 + threadIdx.x) * 4;
    float4 v = *(const float4*)(emb + i);
    bf16x4 r;
    r[0] = (__bf16)v.x; r[1] = (__bf16)v.y; r[2] = (__bf16)v.z; r[3] = (__bf16)v.w;
    *(bf16x4*)(dst + i) = r;
}

// Producer/consumer block: threads 0..511 = 8 consumer waves (MFMA, A from L2),
// threads 512..767 = 4 producer waves (row-contiguous W1 stream -> bf16 -> LDS).
// 8 units = 4 task-groups x 2 K-halves, LDS double-buffered, 1 barrier/unit.
// Producer vmcnt queue = pure HBM staging; consumer queue = pure L2 A-loads.
__global__ __launch_bounds__(768)
void mtc_kernel(const __bf16* __restrict__ embb, const float* __restrict__ W1,
                const float* __restrict__ b1, const float* __restrict__ W2,
                const float* __restrict__ b2, const int* __restrict__ tids,
                float* __restrict__ out)
{
    __shared__ __align__(16) char wlds[2 * BUFB];   // 64 KB
    const int t = threadIdx.x;
    const int blk = blockIdx.x;

    if (t >= 512) {
        // ---------------- producers ----------------
        const int tp = t - 512;            // 0..255
        for (int u = 0; u < 2 * GROUPS; ++u) {
            const int g = u >> 1, hh = u & 1;
            const int tb = (blk * GROUPS + g) * TPB;
            char* buf = &wlds[0] + (u & 1) * BUFB;
            float4 v[16];
#pragma unroll
            for (int j = 0; j < 16; ++j) {
                const int f = tp + j * 256;            // 0..4095 over 32 half-rows
                const int tl = f >> 10;                // task-local 0..3
                const int o  = (f >> 7) & 7;
                const int q  = f & 127;                // float4 within half-row
                const float* p = W1 + (size_t)tids[tb + tl] * (8 * HID)
                               + (size_t)o * HID + hh * HALF + q * 4;
                v[j] = *(const float4*)p;              // 1 KB contiguous per wave-instr
            }
#pragma unroll
            for (int j = 0; j < 16; ++j) {
                const int f = tp + j * 256;
                const int row = f >> 7;                // 0..31 (tl*8 + o)
                const int q   = f & 127;
                bf16x4 r;
                r[0] = (__bf16)v[j].x; r[1] = (__bf16)v[j].y;
                r[2] = (__bf16)v[j].z; r[3] = (__bf16)v[j].w;
                *(bf16x4*)(buf + row * RSTR + ((q * 8) ^ ((row & 7) << 4))) = r;
            }
            __syncthreads();                            // unit u staged
        }
        __syncthreads();                                // pair consumers' last barrier
    } else {
        // ---------------- consumers ----------------
        const int lane = t & 63, w = t >> 6;            // w 0..7, rows w*32..+31
        const __bf16* agp = embb + (size_t)(w * 32 + (lane & 15)) * HID + (lane >> 4) * 8;
        const int xorc = (lane & 7) << 4;
        const int lg16 = (lane >> 4) * 16;
        const int rbase0 = (lane & 15) * RSTR;          // col rows 0..15
        const int rbase1 = (16 + (lane & 15)) * RSTR;   // col rows 16..31

        f32x4 acc[2][2];
        __syncthreads();                                // wait unit 0
        for (int u = 0; u < 2 * GROUPS; ++u) {
            const char* buf = &wlds[0] + (u & 1) * BUFB;
            const __bf16* ag = agp + (u & 1) * HALF;
            if ((u & 1) == 0) {
                const f32x4 z = {0.f, 0.f, 0.f, 0.f};
                acc[0][0] = z; acc[0][1] = z; acc[1][0] = z; acc[1][1] = z;
            }
            bf16x8 a[4][2];                             // 4-deep A prefetch (L2)
#pragma unroll
            for (int s = 0; s < 4; ++s) {
                a[s][0] = *(const bf16x8*)(ag + s * 32);
                a[s][1] = *(const bf16x8*)(ag + s * 32 + 16 * HID);
            }
#pragma unroll
            for (int s = 0; s < 16; ++s) {
                const int sl = s & 3;
                const int off = (s * 64 + lg16) ^ xorc;
                bf16x8 bf0 = *(const bf16x8*)(buf + rbase0 + off);
                bf16x8 bf1 = *(const bf16x8*)(buf + rbase1 + off);
                acc[0][0] = MFMA(a[sl][0], bf0, acc[0][0]);
                acc[0][1] = MFMA(a[sl][0], bf1, acc[0][1]);
                acc[1][0] = MFMA(a[sl][1], bf0, acc[1][0]);
                acc[1][1] = MFMA(a[sl][1], bf1, acc[1][1]);
                if (s + 4 < 16) {
                    a[sl][0] = *(const bf16x8*)(ag + (s + 4) * 32);
                    a[sl][1] = *(const bf16x8*)(ag + (s + 4) * 32 + 16 * HID);
                }
            }
            if (u & 1) {
                // ---- epilogue for group g = u>>1
                const int g = u >> 1;
                const int tb = (blk * GROUPS + g) * TPB;
                const int col = lane & 15;
                const int rgrp = lane >> 4;
                const int o = col & 7;
#pragma unroll
                for (int nt = 0; nt < 2; ++nt) {
                    const int tl = nt * 2 + (col >> 3);       // 0..3
                    const int task = tids[tb + tl];
                    const float bb1 = b1[task * 8 + o];
                    const float ww2 = W2[task * 8 + o];
#pragma unroll
                    for (int mt = 0; mt < 2; ++mt) {
                        float v[4];
#pragma unroll
                        for (int r = 0; r < 4; ++r) {
                            float x = acc[mt][nt][r] + bb1;
                            x = x > 0.f ? x : 0.f;
                            v[r] = x * ww2;
                        }
#pragma unroll
                        for (int m = 1; m <= 4; m <<= 1) {
#pragma unroll
                            for (int r = 0; r < 4; ++r) v[r] += __shfl_xor(v[r], m, 64);
                        }
                        if ((lane & 7) == 0) {
                            const float bb2 = b2[task];
                            const int brow = w * 32 + mt * 16 + rgrp * 4;
                            float4 o4 = make_float4(v[0] + bb2, v[1] + bb2,
                                                    v[2] + bb2, v[3] + bb2);
                            *(float4*)(out + (size_t)(tb + tl) * BATCH + brow) = o4;
                        }
                    }
                }
            }
            __syncthreads();                            // release buffer to producers
        }
    }
}

extern "C" void kernel_launch(void* const* d_in, const int* in_sizes, int n_in,
                              void* d_out, int out_size, void* d_ws, size_t ws_size,
                              hipStream_t stream) {
    const float* emb = (const float*)d_in[0];
    const float* W1  = (const float*)d_in[1];
    const float* b1  = (const float*)d_in[2];
    const float* W2  = (const float*)d_in[3];
    const float* b2  = (const float*)d_in[4];
    const int*   tid = (const int*)d_in[5];
    float* outp = (float*)d_out;
    __bf16* embb = (__bf16*)d_ws;   // 512 KB

    cvt_emb_kernel<<<dim3(BATCH * HID / (256 * 4)), dim3(256), 0, stream>>>(emb, embb);
    mtc_kernel<<<dim3(KTASK / (TPB * GROUPS)), dim3(768), 0, stream>>>(embb, W1, b1, W2, b2, tid, outp);
}

// Round 11
// 85.133 us; speedup vs baseline: 1.0182x; 1.0182x over previous
//
#include <hip/hip_runtime.h>

#define HID 1024
#define BATCH 256
#define KTASK 4096
#define TPB 4                 // tasks per block
#define NROW 32               // TPB*8 LDS rows (cols of C)
#define RSTR 2048             // LDS row stride bytes (bank conflicts fixed by XOR swizzle)
#define LDSB (NROW * RSTR)    // 65536 B -> 2 blocks/CU

typedef __bf16 bf16x8 __attribute__((ext_vector_type(8)));
typedef __bf16 bf16x4 __attribute__((ext_vector_type(4)));
typedef float f32x4 __attribute__((ext_vector_type(4)));

#define MFMA(a, b, c) __builtin_amdgcn_mfma_f32_16x16x32_bf16((a), (b), (c), 0, 0, 0)

__global__ __launch_bounds__(256, 4)
void cvt_emb_kernel(const float* __restrict__ emb, __bf16* __restrict__ dst) {
    int i = (blockIdx.x * 256 + threadIdx.x) * 4;
    float4 v = *(const float4*)(emb + i);
    bf16x4 r;
    r[0] = (__bf16)v.x; r[1] = (__bf16)v.y; r[2] = (__bf16)v.z; r[3] = (__bf16)v.w;
    *(bf16x4*)(dst + i) = r;
}

// Full-K LDS staging: each block streams its 4 tasks' W1 (128 KB fp32 = 8192
// float4) ROW-CONTIGUOUSLY (1 KB per wave-instruction), cvt -> bf16 -> 64 KB
// XOR-swizzled LDS. ONE barrier. Then a barrier-free fully-unrolled 32-step
// MFMA loop (B from LDS, A bf16 from L2 via 4-deep register ring).
// 2 blocks/CU: partner block's compute overlaps this block's HBM staging.
__global__ __launch_bounds__(512, 4)
void mtc_kernel(const __bf16* __restrict__ embb, const float* __restrict__ W1,
                const float* __restrict__ b1, const float* __restrict__ W2,
                const float* __restrict__ b2, const int* __restrict__ tids,
                float* __restrict__ out)
{
    __shared__ __align__(16) char wlds[LDSB];

    const int t = threadIdx.x;
    const int lane = t & 63;
    const int w = t >> 6;                // 0..7
    const int blk = blockIdx.x;          // 0..1023

    int tk[TPB];
#pragma unroll
    for (int i = 0; i < TPB; ++i) tk[i] = tids[blk * TPB + i];

    // ---------------- stage: 32 rows x 4 KB fp32, row-contiguous ----------------
    // flat float4 index f = t + (b*8+j)*512 covers 0..8191 exactly (16/thread).
    // Per wave-instruction: 64 lanes x 16 B = 1 KB contiguous inside one W1 row.
#pragma unroll
    for (int b = 0; b < 2; ++b) {
        float4 v[8];
#pragma unroll
        for (int j = 0; j < 8; ++j) {
            const int f = t + (b * 8 + j) * 512;
            const int row = f >> 8;                  // 0..31 = tl*8 + o
            const float* p = W1 + (size_t)tk[row >> 3] * (8 * HID)
                           + (size_t)(row & 7) * HID + (size_t)(f & 255) * 4;
            v[j] = *(const float4*)p;
        }
#pragma unroll
        for (int j = 0; j < 8; ++j) {
            const int f = t + (b * 8 + j) * 512;
            const int row = f >> 8;
            const int byt = ((f & 255) * 8) ^ ((row & 7) << 4);   // swizzled
            bf16x4 r;
            r[0] = (__bf16)v[j].x; r[1] = (__bf16)v[j].y;
            r[2] = (__bf16)v[j].z; r[3] = (__bf16)v[j].w;
            *(bf16x4*)(&wlds[0] + row * RSTR + byt) = r;
        }
    }
    __syncthreads();    // the only barrier

    // ---------------- compute: 32 k-steps, no barriers ----------------
    // Wave w: M-rows w*32 + mt*16 + (lane&15); cols = LDS rows nt*16 + (lane&15).
    const __bf16* agp = embb + (size_t)(w * 32 + (lane & 15)) * HID + (lane >> 4) * 8;
    const int xorc = (lane & 7) << 4;              // (row&7)<<4, row = lane&15 (+16)
    const int lg16 = (lane >> 4) * 16;
    const char* bp0 = &wlds[0] + (lane & 15) * RSTR;
    const char* bp1 = bp0 + 16 * RSTR;

    f32x4 acc[2][2];
    const f32x4 zero = {0.f, 0.f, 0.f, 0.f};
    acc[0][0] = zero; acc[0][1] = zero; acc[1][0] = zero; acc[1][1] = zero;

    bf16x8 ar[4][2];                       // 4-deep A ring (slot = s&3), 2 M-tiles
#pragma unroll
    for (int s = 0; s < 4; ++s) {
        ar[s][0] = *(const bf16x8*)(agp + s * 32);
        ar[s][1] = *(const bf16x8*)(agp + s * 32 + 16 * HID);
    }
#pragma unroll
    for (int s = 0; s < 32; ++s) {
        const int sl = s & 3;
        const int off = (s * 64 + lg16) ^ xorc;
        bf16x8 b0 = *(const bf16x8*)(bp0 + off);                 // cols 0..15
        bf16x8 b1 = *(const bf16x8*)(bp1 + off);                 // cols 16..31
        acc[0][0] = MFMA(ar[sl][0], b0, acc[0][0]);
        acc[0][1] = MFMA(ar[sl][0], b1, acc[0][1]);
        acc[1][0] = MFMA(ar[sl][1], b0, acc[1][0]);
        acc[1][1] = MFMA(ar[sl][1], b1, acc[1][1]);
        if (s + 4 < 32) {
            ar[sl][0] = *(const bf16x8*)(agp + (s + 4) * 32);
            ar[sl][1] = *(const bf16x8*)(agp + (s + 4) * 32 + 16 * HID);
        }
    }

    // ---- epilogue: +b1, relu, *w2, shuffle-reduce over o (8 lanes), +b2, store
    const int col = lane & 15;
    const int rgrp = lane >> 4;
    const int o = col & 7;
#pragma unroll
    for (int nt = 0; nt < 2; ++nt) {
        const int tl = nt * 2 + (col >> 3);       // task-local 0..3
        const int task = tk[tl];
        const float bb1 = b1[task * 8 + o];
        const float ww2 = W2[task * 8 + o];
#pragma unroll
        for (int mt = 0; mt < 2; ++mt) {
            float v[4];
#pragma unroll
            for (int r = 0; r < 4; ++r) {
                float x = acc[mt][nt][r] + bb1;
                x = x > 0.f ? x : 0.f;
                v[r] = x * ww2;
            }
#pragma unroll
            for (int m = 1; m <= 4; m <<= 1) {
#pragma unroll
                for (int r = 0; r < 4; ++r) v[r] += __shfl_xor(v[r], m, 64);
            }
            if ((lane & 7) == 0) {
                const float bb2 = b2[task];
                const int brow = w * 32 + mt * 16 + rgrp * 4;
                float4 o4 = make_float4(v[0] + bb2, v[1] + bb2, v[2] + bb2, v[3] + bb2);
                *(float4*)(out + (size_t)(blk * TPB + tl) * BATCH + brow) = o4;
            }
        }
    }
}

extern "C" void kernel_launch(void* const* d_in, const int* in_sizes, int n_in,
                              void* d_out, int out_size, void* d_ws, size_t ws_size,
                              hipStream_t stream) {
    const float* emb = (const float*)d_in[0];
    const float* W1  = (const float*)d_in[1];
    const float* b1  = (const float*)d_in[2];
    const float* W2  = (const float*)d_in[3];
    const float* b2  = (const float*)d_in[4];
    const int*   tid = (const int*)d_in[5];
    float* outp = (float*)d_out;
    __bf16* embb = (__bf16*)d_ws;   // 512 KB

    cvt_emb_kernel<<<dim3(BATCH * HID / (256 * 4)), dim3(256), 0, stream>>>(emb, embb);
    mtc_kernel<<<dim3(KTASK / TPB), dim3(512), 0, stream>>>(embb, W1, b1, W2, b2, tid, outp);
}